// Round 20
// baseline (281.929 us; speedup 1.0000x reference)
//
#include <hip/hip_runtime.h>
#include <cmath>

#define D  128   // D_EDGE
#define DR 64    // D_RBF

typedef float fx4    __attribute__((ext_vector_type(4)));
typedef float f32x16 __attribute__((ext_vector_type(16)));
typedef short short8v __attribute__((ext_vector_type(8)));

__device__ __forceinline__ float ssp_f(float x) {
  // softplus(x) - log(2), numerically stable
  float m = fmaxf(x, 0.0f);
  float t = __expf(-fabsf(x));
  return m + __logf(1.0f + t) - 0.69314718055994531f;
}

__device__ __forceinline__ short f2bf(float f) {   // fp32 -> bf16 (RNE)
  unsigned u = __float_as_uint(f);
  u = (u + 0x7FFFu + ((u >> 16) & 1u)) >> 16;
  return (short)u;
}

__device__ __forceinline__ float bf2f(unsigned short h) {  // bf16 -> fp32
  return __uint_as_float(((unsigned)h) << 16);
}

__device__ __forceinline__ short8v cvt8(const float* p) {  // 8 f32 -> bf16x8
  fx4 lo = *(const fx4*)p;
  fx4 hi = *(const fx4*)(p + 4);
  short8v r;
  r[0] = f2bf(lo.x); r[1] = f2bf(lo.y); r[2] = f2bf(lo.z); r[3] = f2bf(lo.w);
  r[4] = f2bf(hi.x); r[5] = f2bf(hi.y); r[6] = f2bf(hi.z); r[7] = f2bf(hi.w);
  return r;
}

// ---------------------------------------------------------------------------
// prep kernel (R19, unchanged): blocks [0,nbt) = MFMA table GEMM -> bf16
// PjH/PiH; blocks [nbt,nbt+32) = stage0 (weff fp32+bf16, beff).
// ---------------------------------------------------------------------------
__global__ __launch_bounds__(256) void prep_kernel(
    const float* __restrict__ vi, const float* __restrict__ W_cat,
    const float* __restrict__ W_rbf, const float* __restrict__ b_rbf,
    const float* __restrict__ b_cat,
    unsigned short* __restrict__ PjH, unsigned short* __restrict__ PiH,
    float* __restrict__ weff, unsigned short* __restrict__ weffh,
    float* __restrict__ beff, int N, int nbt, int write_bf16)
{
  const int t = threadIdx.x;
  if ((int)blockIdx.x >= nbt) {
    int gid = ((int)blockIdx.x - nbt) * 256 + t;
    if (gid < D * DR) {
      int o = gid >> 6;
      int r = gid & 63;
      float acc = 0.0f;
      #pragma unroll 8
      for (int d = 0; d < D; ++d)
        acc = fmaf(W_cat[o * 384 + d], W_rbf[d * DR + r], acc);
      weff[gid] = acc;
      if (write_bf16) weffh[gid] = (unsigned short)f2bf(acc);
    }
    if (gid < D) {
      float acc = b_cat[gid];
      #pragma unroll 8
      for (int d = 0; d < D; ++d)
        acc = fmaf(b_rbf[d], W_cat[gid * 384 + d], acc);
      beff[gid] = acc;
    }
    return;
  }

  const int lane = t & 63;
  const int col  = lane & 31;
  const int half = lane >> 5;
  const long wid  = (long)blockIdx.x * 4 + (t >> 6);
  const long base = wid * 64;
  if (base >= (long)N) return;

  #pragma unroll
  for (int tile = 0; tile < 2; ++tile) {
    const long tb = base + (long)tile * 32;
    if (tb >= (long)N) break;
    long nr = tb + col; if (nr > (long)N - 1) nr = (long)N - 1;

    const float* arow = vi + nr * D + half * 8;
    short8v A[8];
    #pragma unroll
    for (int ks = 0; ks < 8; ++ks)
      A[ks] = cvt8(&arow[ks * 16]);

    #pragma unroll
    for (int ct = 0; ct < 8; ++ct) {
      const int off = 128 + (ct >> 2) * 128;
      const int o   = (ct & 3) * 32 + col;
      const float* wrow = W_cat + (long)o * 384 + off + half * 8;

      f32x16 acc = (f32x16)(0.0f);
      #pragma unroll
      for (int ks = 0; ks < 8; ++ks) {
        short8v Bv = cvt8(&wrow[ks * 16]);
        acc = __builtin_amdgcn_mfma_f32_32x32x16_bf16(A[ks], Bv, acc, 0, 0, 0);
      }

      unsigned short* P = (ct < 4) ? PjH : PiH;
      const int cb = (ct & 3) * 32;
      #pragma unroll
      for (int reg = 0; reg < 16; ++reg) {
        const int erl = (reg & 3) + 8 * (reg >> 2) + 4 * half;
        const long nn = tb + erl;
        if (nn < (long)N)
          P[nn * D + cb + col] = (unsigned short)f2bf(acc[reg]);
      }
    }
  }
}

// ---------------------------------------------------------------------------
// MFMA edge kernel v7: 16x16x32, wave = 16 edges x 8 chan-steps, depth-2
// gather pipeline, budget <=64 VGPR (the 8-waves/SIMD tier).
// Matrix of prior evidence: no-pipe@4w=205us (R16), pipe@2w=257 (R12/R14,
// VGPR>128), no-pipe@8w+2x bytes=257 (R15). This is the untested cell:
// pipe + high tier + low traffic (bf16 tables, NT streams, packed stores).
// C/D (m89-verified): col=lane&15 (chan), row=(lane>>4)*4+reg (edge).
// A/B k-map: k=kg*8+i (+32 frag1), same bijection both sides.
// Gathers loaded RAW (ushort) into the double buffer; bf16->f32 convert
// deferred to the epilogue so the loads aren't serialized by converts.
// NOTE: never set min-waves launch bounds (R3/R13: forced caps -> 900MB
// scratch spill).
// ---------------------------------------------------------------------------
__global__ __launch_bounds__(64) void edge_mfma_kernel(
    const float* __restrict__ rbf, const int* __restrict__ eidx,
    const unsigned short* __restrict__ weffh, const float* __restrict__ beff,
    const unsigned short* __restrict__ PjH, const unsigned short* __restrict__ PiH,
    float* __restrict__ out, int E)
{
  const int lane = threadIdx.x & 63;
  const int n16  = lane & 15;   // channel within 16-step
  const int kg   = lane >> 4;   // k-group / C-row-group
  const long tb  = (long)blockIdx.x * 16;
  if (tb >= (long)E) return;

  // ---- A fragments: rbf row (tb+n16), NT ----
  long ar = tb + n16; if (ar > (long)E - 1) ar = (long)E - 1;
  const float* arow = rbf + ar * DR + kg * 8;
  short8v A0, A1;
  {
    fx4 l0 = __builtin_nontemporal_load((const fx4*)&arow[0]);
    fx4 h0 = __builtin_nontemporal_load((const fx4*)&arow[4]);
    fx4 l1 = __builtin_nontemporal_load((const fx4*)&arow[32]);
    fx4 h1 = __builtin_nontemporal_load((const fx4*)&arow[36]);
    A0[0] = f2bf(l0.x); A0[1] = f2bf(l0.y); A0[2] = f2bf(l0.z); A0[3] = f2bf(l0.w);
    A0[4] = f2bf(h0.x); A0[5] = f2bf(h0.y); A0[6] = f2bf(h0.z); A0[7] = f2bf(h0.w);
    A1[0] = f2bf(l1.x); A1[1] = f2bf(l1.y); A1[2] = f2bf(l1.z); A1[3] = f2bf(l1.w);
    A1[4] = f2bf(h1.x); A1[5] = f2bf(h1.y); A1[6] = f2bf(h1.z); A1[7] = f2bf(h1.w);
  }

  // ---- per-reg byte offsets (C/D edge row m = kg*4 + reg) ----
  int joff[4], ioff[4], soff[4];
  bool ok[4];
  #pragma unroll
  for (int reg = 0; reg < 4; ++reg) {
    const long ge = tb + kg * 4 + reg;
    ok[reg] = ge < (long)E;
    const long gc = ok[reg] ? ge : (long)E - 1;
    joff[reg] = eidx[(long)E + gc] * 256 + n16 * 2;   // j*128ch*2B + chan
    ioff[reg] = eidx[gc] * 256 + n16 * 2;
    soff[reg] = (int)(ge * 512) + n16 * 4;            // e*128ch*4B + chan
  }

  const char* PjB = (const char*)PjH;
  const char* PiB = (const char*)PiH;
  char* outB = (char*)out;

#define ISSUE_G(gjv, giv, ct)                                                  \
  { _Pragma("unroll")                                                          \
    for (int reg = 0; reg < 4; ++reg) {                                        \
      gjv[reg] = *(const unsigned short*)(PjB + (long)joff[reg] + (ct) * 32);  \
      giv[reg] = *(const unsigned short*)(PiB + (long)ioff[reg] + (ct) * 32);  \
    } }

#define COMPUTE(ct, gjv, giv)                                                  \
  { short8v B0 = *(const short8v*)&weffh[((ct) * 16 + n16) * DR + kg * 8];     \
    short8v B1 = *(const short8v*)&weffh[((ct) * 16 + n16) * DR + 32 + kg * 8];\
    const float bias = beff[(ct) * 16 + n16];                                  \
    fx4 acc = {bias, bias, bias, bias};                                        \
    acc = __builtin_amdgcn_mfma_f32_16x16x32_bf16(A0, B0, acc, 0, 0, 0);       \
    acc = __builtin_amdgcn_mfma_f32_16x16x32_bf16(A1, B1, acc, 0, 0, 0);       \
    _Pragma("unroll")                                                          \
    for (int reg = 0; reg < 4; ++reg) {                                        \
      const float v = ssp_f(acc[reg] + bf2f(gjv[reg]) + bf2f(giv[reg]));       \
      if (ok[reg])                                                             \
        __builtin_nontemporal_store(v, (float*)(outB + (long)soff[reg] + (ct) * 64)); \
    } }

  unsigned short gjA[4], giA[4], gjB[4], giB[4];

  ISSUE_G(gjA, giA, 0);
  #pragma unroll
  for (int c2 = 0; c2 < 4; ++c2) {
    const int ct0 = 2 * c2, ct1 = 2 * c2 + 1;
    ISSUE_G(gjB, giB, ct1);
    __builtin_amdgcn_sched_barrier(0);   // pin issue ahead of compute
    COMPUTE(ct0, gjA, giA);
    if (ct0 + 2 < 8) { ISSUE_G(gjA, giA, ct0 + 2); }
    __builtin_amdgcn_sched_barrier(0);
    COMPUTE(ct1, gjB, giB);
  }

#undef ISSUE_G
#undef COMPUTE
}

// ---------------------------------------------------------------------------
// Fallback (only if d_ws is too small): 3 additive passes over out, fp32.
// ---------------------------------------------------------------------------
template<int K, int WS, int WOFF, bool GATHER, bool INIT, bool FINAL>
__global__ __launch_bounds__(256) void pass_kernel(
    const float* __restrict__ src, const int* __restrict__ gidx,
    const float* __restrict__ W, const float* __restrict__ beff,
    float* __restrict__ out, int E)
{
  int e = blockIdx.x * 256 + threadIdx.x;
  if (e >= E) return;
  long rowi = GATHER ? (long)gidx[e] : (long)e;

  float4 rv[K / 4];
  const float4* sp = (const float4*)(src + rowi * K);
  #pragma unroll
  for (int c = 0; c < K / 4; ++c) rv[c] = sp[c];

  float* orow = out + (long)e * D;
  for (int ob = 0; ob < D; ob += 4) {
    float acc[4];
    if (INIT) {
      float4 b4 = *(const float4*)&beff[ob];
      acc[0] = b4.x; acc[1] = b4.y; acc[2] = b4.z; acc[3] = b4.w;
    } else {
      float4 p4 = *(const float4*)&orow[ob];
      acc[0] = p4.x; acc[1] = p4.y; acc[2] = p4.z; acc[3] = p4.w;
    }
    #pragma unroll
    for (int k = 0; k < 4; ++k) {
      const float4* wv = (const float4*)&W[(long)(ob + k) * WS + WOFF];
      float a = acc[k];
      #pragma unroll
      for (int c = 0; c < K / 4; ++c) {
        float4 w4 = wv[c]; float4 r4 = rv[c];
        a = fmaf(w4.x, r4.x, a); a = fmaf(w4.y, r4.y, a);
        a = fmaf(w4.z, r4.z, a); a = fmaf(w4.w, r4.w, a);
      }
      acc[k] = a;
    }
    float4 o4;
    o4.x = FINAL ? ssp_f(acc[0]) : acc[0];
    o4.y = FINAL ? ssp_f(acc[1]) : acc[1];
    o4.z = FINAL ? ssp_f(acc[2]) : acc[2];
    o4.w = FINAL ? ssp_f(acc[3]) : acc[3];
    *(float4*)&orow[ob] = o4;
  }
}

// ---------------------------------------------------------------------------
extern "C" void kernel_launch(void* const* d_in, const int* in_sizes, int n_in,
                              void* d_out, int out_size, void* d_ws, size_t ws_size,
                              hipStream_t stream)
{
  const float* vi    = (const float*)d_in[0];
  const float* rbf   = (const float*)d_in[1];
  const float* W_rbf = (const float*)d_in[2];
  const float* b_rbf = (const float*)d_in[3];
  const float* W_cat = (const float*)d_in[4];
  const float* b_cat = (const float*)d_in[5];
  const int*   eidx  = (const int*)d_in[6];

  const int N = in_sizes[0] / D;
  const int E = in_sizes[6] / 2;
  float* out = (float*)d_out;

  float* ws   = (float*)d_ws;
  float* weff = ws;                               // 8192 floats
  float* beff = ws + D * DR;                      // 128 floats (ends 8320)
  unsigned short* weffh = (unsigned short*)(ws + 8448);   // 8192 ushort
  unsigned short* PjH = (unsigned short*)(ws + 8448 + 4096);  // N*128 ushort
  unsigned short* PiH = PjH + (size_t)N * D;
  size_t need = (8448 + 4096 + (size_t)N * 128) * sizeof(float);

  const int use_fast = (ws_size >= need && E >= 1);

  if (use_fast) {
    long twaves = ((long)N + 63) / 64;
    int nbt = (int)((twaves + 3) / 4);
    prep_kernel<<<nbt + 32, 256, 0, stream>>>(vi, W_cat, W_rbf, b_rbf, b_cat,
                                              PjH, PiH, weff, weffh, beff,
                                              N, nbt, 1);
    int fblocks = (int)(((long)E + 15) / 16);   // one wave (16 edges) / block
    edge_mfma_kernel<<<fblocks, 64, 0, stream>>>(rbf, eidx, weffh, beff,
                                                 PjH, PiH, out, E);
  } else {
    prep_kernel<<<32, 256, 0, stream>>>(vi, W_cat, W_rbf, b_rbf, b_cat,
                                        PjH, PiH, weff, weffh, beff,
                                        N, 0, 0);
    int eblocks = (E + 255) / 256;
    pass_kernel<DR, DR, 0,  false, true,  false><<<eblocks, 256, 0, stream>>>(rbf, nullptr,  weff,  beff, out, E);
    pass_kernel<D, 384, 128, true, false, false><<<eblocks, 256, 0, stream>>>(vi,  eidx + E, W_cat, beff, out, E);
    pass_kernel<D, 384, 256, true, false, true ><<<eblocks, 256, 0, stream>>>(vi,  eidx,     W_cat, beff, out, E);
  }
}

// Round 21
// 246.092 us; speedup vs baseline: 1.1456x; 1.1456x over previous
//
#include <hip/hip_runtime.h>
#include <cmath>

#define D  128   // D_EDGE
#define DR 64    // D_RBF

typedef float fx4    __attribute__((ext_vector_type(4)));
typedef float f32x16 __attribute__((ext_vector_type(16)));
typedef short short8v __attribute__((ext_vector_type(8)));

__device__ __forceinline__ float ssp_f(float x) {
  // softplus(x) - log(2), numerically stable
  float m = fmaxf(x, 0.0f);
  float t = __expf(-fabsf(x));
  return m + __logf(1.0f + t) - 0.69314718055994531f;
}

__device__ __forceinline__ short f2bf(float f) {   // fp32 -> bf16 (RNE)
  unsigned u = __float_as_uint(f);
  u = (u + 0x7FFFu + ((u >> 16) & 1u)) >> 16;
  return (short)u;
}

__device__ __forceinline__ float bf2f(unsigned short h) {  // bf16 -> fp32
  return __uint_as_float(((unsigned)h) << 16);
}

__device__ __forceinline__ short8v cvt8(const float* p) {  // 8 f32 -> bf16x8
  fx4 lo = *(const fx4*)p;
  fx4 hi = *(const fx4*)(p + 4);
  short8v r;
  r[0] = f2bf(lo.x); r[1] = f2bf(lo.y); r[2] = f2bf(lo.z); r[3] = f2bf(lo.w);
  r[4] = f2bf(hi.x); r[5] = f2bf(hi.y); r[6] = f2bf(hi.z); r[7] = f2bf(hi.w);
  return r;
}

// ---------------------------------------------------------------------------
// prep kernel (R19, proven ~20us): blocks [0,nbt) = MFMA table GEMM -> bf16
// PjH/PiH; blocks [nbt,nbt+32) = stage0 (weff fp32+bf16, beff).
// ---------------------------------------------------------------------------
__global__ __launch_bounds__(256) void prep_kernel(
    const float* __restrict__ vi, const float* __restrict__ W_cat,
    const float* __restrict__ W_rbf, const float* __restrict__ b_rbf,
    const float* __restrict__ b_cat,
    unsigned short* __restrict__ PjH, unsigned short* __restrict__ PiH,
    float* __restrict__ weff, unsigned short* __restrict__ weffh,
    float* __restrict__ beff, int N, int nbt, int write_bf16)
{
  const int t = threadIdx.x;
  if ((int)blockIdx.x >= nbt) {
    int gid = ((int)blockIdx.x - nbt) * 256 + t;
    if (gid < D * DR) {
      int o = gid >> 6;
      int r = gid & 63;
      float acc = 0.0f;
      #pragma unroll 8
      for (int d = 0; d < D; ++d)
        acc = fmaf(W_cat[o * 384 + d], W_rbf[d * DR + r], acc);
      weff[gid] = acc;
      if (write_bf16) weffh[gid] = (unsigned short)f2bf(acc);
    }
    if (gid < D) {
      float acc = b_cat[gid];
      #pragma unroll 8
      for (int d = 0; d < D; ++d)
        acc = fmaf(b_rbf[d], W_cat[gid * 384 + d], acc);
      beff[gid] = acc;
    }
    return;
  }

  const int lane = t & 63;
  const int col  = lane & 31;
  const int half = lane >> 5;
  const long wid  = (long)blockIdx.x * 4 + (t >> 6);
  const long base = wid * 64;
  if (base >= (long)N) return;

  #pragma unroll
  for (int tile = 0; tile < 2; ++tile) {
    const long tb = base + (long)tile * 32;
    if (tb >= (long)N) break;
    long nr = tb + col; if (nr > (long)N - 1) nr = (long)N - 1;

    const float* arow = vi + nr * D + half * 8;
    short8v A[8];
    #pragma unroll
    for (int ks = 0; ks < 8; ++ks)
      A[ks] = cvt8(&arow[ks * 16]);

    #pragma unroll
    for (int ct = 0; ct < 8; ++ct) {
      const int off = 128 + (ct >> 2) * 128;
      const int o   = (ct & 3) * 32 + col;
      const float* wrow = W_cat + (long)o * 384 + off + half * 8;

      f32x16 acc = (f32x16)(0.0f);
      #pragma unroll
      for (int ks = 0; ks < 8; ++ks) {
        short8v Bv = cvt8(&wrow[ks * 16]);
        acc = __builtin_amdgcn_mfma_f32_32x32x16_bf16(A[ks], Bv, acc, 0, 0, 0);
      }

      unsigned short* P = (ct < 4) ? PjH : PiH;
      const int cb = (ct & 3) * 32;
      #pragma unroll
      for (int reg = 0; reg < 16; ++reg) {
        const int erl = (reg & 3) + 8 * (reg >> 2) + 4 * half;
        const long nn = tb + erl;
        if (nn < (long)N)
          P[nn * D + cb + col] = (unsigned short)f2bf(acc[reg]);
      }
    }
  }
}

// ---------------------------------------------------------------------------
// MFMA edge kernel (R16/R18/R19 structure — the robust ~205us optimum).
// One-wave blocks; full-line coalesced gathers (col=channel on lanes),
// bf16 tables, NT streaming rbf/out.
// Exhausted-axes evidence: bytes -33% null (R16); occupancy 21->76% worse
// (R15/R20); VMEM-instr -3.3x worse (R17); 1-wave dispatch null (R18);
// gather pipelining worse (R12/R14/R20). Bound: random 64B-granule L2/L3
// gather throughput (~1.6 TB/s table reads + streams = 2.8 TB/s effective).
// NOTE: never set min-waves launch bounds (R3/R13: forced caps -> 900MB
// scratch spill).
// ---------------------------------------------------------------------------
__global__ __launch_bounds__(64) void edge_mfma_kernel(
    const float* __restrict__ rbf, const int* __restrict__ eidx,
    const unsigned short* __restrict__ weffh, const float* __restrict__ beff,
    const unsigned short* __restrict__ PjH, const unsigned short* __restrict__ PiH,
    float* __restrict__ out, int E)
{
  const int lane = threadIdx.x & 63;
  const int row  = lane & 31;   // A row / B col / C col (channel)
  const int half = lane >> 5;   // k-half selector
  const long base = (long)blockIdx.x * 64;
  if (base >= (long)E) return;

  // B fragments: B[k][n] = weff[n*64+k] (bf16), n=ct*32+row, k=ks*16+8*half+i
  short8v B[4][4];
  #pragma unroll
  for (int ct = 0; ct < 4; ++ct) {
    #pragma unroll
    for (int ks = 0; ks < 4; ++ks)
      B[ct][ks] = *(const short8v*)&weffh[(ct * 32 + row) * DR + ks * 16 + half * 8];
  }
  float bias[4];
  #pragma unroll
  for (int ct = 0; ct < 4; ++ct) bias[ct] = beff[ct * 32 + row];

  #pragma unroll
  for (int tile = 0; tile < 2; ++tile) {
    const long tb = base + (long)tile * 32;
    if (tb >= (long)E) break;
    long er = tb + row; if (er > (long)E - 1) er = (long)E - 1;

    // A fragments straight from global (fp32 -> bf16), NT (read-once stream)
    const float* arow = rbf + er * DR + half * 8;
    short8v A[4];
    #pragma unroll
    for (int ks = 0; ks < 4; ++ks) {
      fx4 lo = __builtin_nontemporal_load((const fx4*)&arow[ks * 16]);
      fx4 hi = __builtin_nontemporal_load((const fx4*)&arow[ks * 16 + 4]);
      short8v a;
      a[0] = f2bf(lo.x); a[1] = f2bf(lo.y); a[2] = f2bf(lo.z); a[3] = f2bf(lo.w);
      a[4] = f2bf(hi.x); a[5] = f2bf(hi.y); a[6] = f2bf(hi.z); a[7] = f2bf(hi.w);
      A[ks] = a;
    }

    // per-lane edge indices for this tile (lane's row = local edge id)
    const int iv = eidx[er];            // edge_index[0] -> h_i -> Pi
    const int jv = eidx[(long)E + er];  // edge_index[1] -> h_j -> Pj

    #pragma unroll
    for (int ct = 0; ct < 4; ++ct) {
      // gathers: 32 bf16 loads in flight (full-line coalesced per instr)
      float gj[16], gi[16];
      #pragma unroll
      for (int reg = 0; reg < 16; ++reg) {
        const int erl = (reg & 3) + 8 * (reg >> 2) + 4 * half;
        const int j = __shfl(jv, erl);
        const int i = __shfl(iv, erl);
        gj[reg] = bf2f(PjH[(long)j * D + ct * 32 + row]);
        gi[reg] = bf2f(PiH[(long)i * D + ct * 32 + row]);
      }
      __builtin_amdgcn_sched_barrier(0);   // keep gather issue ahead of MFMA

      f32x16 acc = (f32x16)(0.0f);
      acc = __builtin_amdgcn_mfma_f32_32x32x16_bf16(A[0], B[ct][0], acc, 0, 0, 0);
      acc = __builtin_amdgcn_mfma_f32_32x32x16_bf16(A[1], B[ct][1], acc, 0, 0, 0);
      acc = __builtin_amdgcn_mfma_f32_32x32x16_bf16(A[2], B[ct][2], acc, 0, 0, 0);
      acc = __builtin_amdgcn_mfma_f32_32x32x16_bf16(A[3], B[ct][3], acc, 0, 0, 0);

      #pragma unroll
      for (int reg = 0; reg < 16; ++reg) {
        const int erl = (reg & 3) + 8 * (reg >> 2) + 4 * half;
        const long ge = tb + erl;
        const float v = ssp_f(acc[reg] + gj[reg] + gi[reg] + bias[ct]);
        if (ge < (long)E)
          __builtin_nontemporal_store(v, &out[ge * D + ct * 32 + row]);
      }
    }
  }
}

// ---------------------------------------------------------------------------
// Fallback (only if d_ws is too small): 3 additive passes over out, fp32.
// ---------------------------------------------------------------------------
template<int K, int WS, int WOFF, bool GATHER, bool INIT, bool FINAL>
__global__ __launch_bounds__(256) void pass_kernel(
    const float* __restrict__ src, const int* __restrict__ gidx,
    const float* __restrict__ W, const float* __restrict__ beff,
    float* __restrict__ out, int E)
{
  int e = blockIdx.x * 256 + threadIdx.x;
  if (e >= E) return;
  long rowi = GATHER ? (long)gidx[e] : (long)e;

  float4 rv[K / 4];
  const float4* sp = (const float4*)(src + rowi * K);
  #pragma unroll
  for (int c = 0; c < K / 4; ++c) rv[c] = sp[c];

  float* orow = out + (long)e * D;
  for (int ob = 0; ob < D; ob += 4) {
    float acc[4];
    if (INIT) {
      float4 b4 = *(const float4*)&beff[ob];
      acc[0] = b4.x; acc[1] = b4.y; acc[2] = b4.z; acc[3] = b4.w;
    } else {
      float4 p4 = *(const float4*)&orow[ob];
      acc[0] = p4.x; acc[1] = p4.y; acc[2] = p4.z; acc[3] = p4.w;
    }
    #pragma unroll
    for (int k = 0; k < 4; ++k) {
      const float4* wv = (const float4*)&W[(long)(ob + k) * WS + WOFF];
      float a = acc[k];
      #pragma unroll
      for (int c = 0; c < K / 4; ++c) {
        float4 w4 = wv[c]; float4 r4 = rv[c];
        a = fmaf(w4.x, r4.x, a); a = fmaf(w4.y, r4.y, a);
        a = fmaf(w4.z, r4.z, a); a = fmaf(w4.w, r4.w, a);
      }
      acc[k] = a;
    }
    float4 o4;
    o4.x = FINAL ? ssp_f(acc[0]) : acc[0];
    o4.y = FINAL ? ssp_f(acc[1]) : acc[1];
    o4.z = FINAL ? ssp_f(acc[2]) : acc[2];
    o4.w = FINAL ? ssp_f(acc[3]) : acc[3];
    *(float4*)&orow[ob] = o4;
  }
}

// ---------------------------------------------------------------------------
extern "C" void kernel_launch(void* const* d_in, const int* in_sizes, int n_in,
                              void* d_out, int out_size, void* d_ws, size_t ws_size,
                              hipStream_t stream)
{
  const float* vi    = (const float*)d_in[0];
  const float* rbf   = (const float*)d_in[1];
  const float* W_rbf = (const float*)d_in[2];
  const float* b_rbf = (const float*)d_in[3];
  const float* W_cat = (const float*)d_in[4];
  const float* b_cat = (const float*)d_in[5];
  const int*   eidx  = (const int*)d_in[6];

  const int N = in_sizes[0] / D;
  const int E = in_sizes[6] / 2;
  float* out = (float*)d_out;

  float* ws   = (float*)d_ws;
  float* weff = ws;                               // 8192 floats
  float* beff = ws + D * DR;                      // 128 floats (ends 8320)
  unsigned short* weffh = (unsigned short*)(ws + 8448);   // 8192 ushort
  unsigned short* PjH = (unsigned short*)(ws + 8448 + 4096);  // N*128 ushort
  unsigned short* PiH = PjH + (size_t)N * D;
  size_t need = (8448 + 4096 + (size_t)N * 128) * sizeof(float);

  const int use_fast = (ws_size >= need && E >= 1);

  if (use_fast) {
    long twaves = ((long)N + 63) / 64;
    int nbt = (int)((twaves + 3) / 4);           // table-GEMM blocks
    prep_kernel<<<nbt + 32, 256, 0, stream>>>(vi, W_cat, W_rbf, b_rbf, b_cat,
                                              PjH, PiH, weff, weffh, beff,
                                              N, nbt, 1);
    int fblocks = (int)(((long)E + 63) / 64);    // one wave (64 edges) / block
    edge_mfma_kernel<<<fblocks, 64, 0, stream>>>(rbf, eidx, weffh, beff,
                                                 PjH, PiH, out, E);
  } else {
    prep_kernel<<<32, 256, 0, stream>>>(vi, W_cat, W_rbf, b_rbf, b_cat,
                                        PjH, PiH, weff, weffh, beff,
                                        N, 0, 0);
    int eblocks = (E + 255) / 256;
    pass_kernel<DR, DR, 0,  false, true,  false><<<eblocks, 256, 0, stream>>>(rbf, nullptr,  weff,  beff, out, E);
    pass_kernel<D, 384, 128, true, false, false><<<eblocks, 256, 0, stream>>>(vi,  eidx + E, W_cat, beff, out, E);
    pass_kernel<D, 384, 256, true, false, true ><<<eblocks, 256, 0, stream>>>(vi,  eidx,     W_cat, beff, out, E);
  }
}